// Round 3
// baseline (256.536 us; speedup 1.0000x reference)
//
#include <hip/hip_runtime.h>

// ===========================================================================
// Layouts: the low-res chain uses HWC (channel-last) so that wave-convs with
// lane=channel get fully coalesced loads. The bilateral grid is stored
// cell-major [N][8][16][16][12] so the slice gathers 12 coeffs as 3x float4.
// ===========================================================================

// ---------------------------------------------------------------------------
// conv1: lowres CHW [N,3,256,256] -> x1 HWC [N,128,128,8], stride 2, relu.
// Thread per output element, co fastest for coalesced writes.
// ---------------------------------------------------------------------------
__global__ void conv1_hwc_k(const float* __restrict__ in, const float* __restrict__ w,
                            const float* __restrict__ b, float* __restrict__ out)
{
    int t = blockIdx.x * blockDim.x + threadIdx.x;
    const int total = 2 * 128 * 128 * 8;
    if (t >= total) return;
    int co = t & 7;
    int ow = (t >> 3) & 127;
    int oh = (t >> 10) & 127;
    int n  = t >> 17;

    float acc = b[co];
    #pragma unroll
    for (int ci = 0; ci < 3; ++ci) {
        const float* ib = in + ((size_t)(n * 3 + ci)) * 65536;
        const float* wb = w + ((size_t)co * 3 + ci) * 9;
        #pragma unroll
        for (int kh = 0; kh < 3; ++kh) {
            int ih = oh * 2 - 1 + kh;
            if (ih < 0 || ih >= 256) continue;
            #pragma unroll
            for (int kw = 0; kw < 3; ++kw) {
                int iw = ow * 2 - 1 + kw;
                if (iw < 0 || iw >= 256) continue;
                acc = fmaf(ib[ih * 256 + iw], wb[kh * 3 + kw], acc);
            }
        }
    }
    out[t] = fmaxf(acc, 0.0f);
}

// ---------------------------------------------------------------------------
// Wave conv, HWC in/out. Each 64-lane wave computes OPW=64/CIN consecutive
// outputs (same pixel, consecutive co); lane = input channel. Input loads are
// contiguous CIN*4B segments (fully coalesced, broadcast across subgroups).
// ---------------------------------------------------------------------------
template <int CIN>
__global__ void convw_hwc_k(const float* __restrict__ in, const float* __restrict__ w,
                            const float* __restrict__ b, float* __restrict__ out,
                            int N, int Hin, int Win, int Cout, int Hout, int Wout,
                            int stride, int do_relu)
{
    constexpr int OPW = 64 / CIN;
    int lane = threadIdx.x & 63;
    int wid  = (blockIdx.x * blockDim.x + threadIdx.x) >> 6;
    int sub  = lane / CIN;
    int cl   = lane % CIN;
    int o    = wid * OPW + sub;          // HWC linear output index (co fastest)
    int total = N * Hout * Wout * Cout;

    float acc = 0.0f;
    if (o < total) {
        int co  = o % Cout;
        int pix = o / Cout;
        int ow  = pix % Wout;
        int oh  = (pix / Wout) % Hout;
        int n   = pix / (Wout * Hout);
        const float* wb = w + ((size_t)co * CIN + cl) * 9;
        #pragma unroll
        for (int kh = 0; kh < 3; ++kh) {
            int ih = oh * stride - 1 + kh;
            if (ih < 0 || ih >= Hin) continue;
            const float* ib = in + (((size_t)(n * Hin + ih)) * Win) * CIN + cl;
            #pragma unroll
            for (int kw = 0; kw < 3; ++kw) {
                int iw = ow * stride - 1 + kw;
                if (iw < 0 || iw >= Win) continue;
                acc = fmaf(ib[(size_t)iw * CIN], wb[kh * 3 + kw], acc);
            }
        }
    }
    #pragma unroll
    for (int off = CIN / 2; off >= 1; off >>= 1)
        acc += __shfl_xor(acc, off, 64);

    if (o < total && cl == 0) {
        if (b) acc += b[o % Cout];
        if (do_relu) acc = fmaxf(acc, 0.0f);
        out[o] = acc;
    }
}

// ---------------------------------------------------------------------------
// Fused FC head: fc3(1024->256,relu) -> fc4(256->128,relu) -> fc5(128->64).
// One block of 1024 threads per batch item. g2 is HWC [4][4][64]; fc3 weights
// expect CHW flat (c*16+p), handled by permuted input addressing (g2 is tiny
// and L1-hot; weight reads stay coalesced).
// ---------------------------------------------------------------------------
__global__ void fc_head_k(const float* __restrict__ g2,   // [N][16][64] HWC
                          const float* __restrict__ fw3, const float* __restrict__ fb3,
                          const float* __restrict__ fw4, const float* __restrict__ fb4,
                          const float* __restrict__ fw5, const float* __restrict__ fb5,
                          float* __restrict__ glob)       // [N][64]
{
    __shared__ float s3[256];
    __shared__ float s4[128];
    int n    = blockIdx.x;
    int lane = threadIdx.x & 63;
    int wv   = threadIdx.x >> 6;          // 16 waves
    const float* g2n = g2 + (size_t)n * 1024;

    // fc3: 256 outputs, wave-per-output (16 outputs per wave)
    for (int k = 0; k < 16; ++k) {
        int o = wv * 16 + k;
        const float* wb = fw3 + (size_t)o * 1024;
        float acc = 0.0f;
        for (int j = lane; j < 1024; j += 64) {
            float v = g2n[(j & 15) * 64 + (j >> 4)];   // CHW j -> HWC addr
            acc = fmaf(v, wb[j], acc);
        }
        #pragma unroll
        for (int off = 32; off >= 1; off >>= 1) acc += __shfl_xor(acc, off, 64);
        if (lane == 0) s3[o] = fmaxf(acc + fb3[o], 0.0f);
    }
    __syncthreads();

    // fc4: 128 outputs
    for (int k = 0; k < 8; ++k) {
        int o = wv * 8 + k;
        const float* wb = fw4 + (size_t)o * 256;
        float acc = 0.0f;
        #pragma unroll
        for (int j = lane; j < 256; j += 64) acc = fmaf(s3[j], wb[j], acc);
        #pragma unroll
        for (int off = 32; off >= 1; off >>= 1) acc += __shfl_xor(acc, off, 64);
        if (lane == 0) s4[o] = fmaxf(acc + fb4[o], 0.0f);
    }
    __syncthreads();

    // fc5: 64 outputs (no relu)
    for (int k = 0; k < 4; ++k) {
        int o = wv * 4 + k;
        const float* wb = fw5 + (size_t)o * 128;
        float acc = 0.0f;
        #pragma unroll
        for (int j = lane; j < 128; j += 64) acc = fmaf(s4[j], wb[j], acc);
        #pragma unroll
        for (int off = 32; off >= 1; off >>= 1) acc += __shfl_xor(acc, off, 64);
        if (lane == 0) glob[(size_t)n * 64 + o] = acc + fb5[o];
    }
}

// ---------------------------------------------------------------------------
// fusion = relu(loc + glob); grid = pw @ fusion + pb, written CELL-MAJOR:
// gridc[((n*8+z)*256 + y*16+x)*12 + c] where original co = c*8+z.
// Thread t = linear index into gridc (coalesced writes). loc is HWC.
// ---------------------------------------------------------------------------
__global__ void fusion_grid_k(const float* __restrict__ loc, const float* __restrict__ glob,
                              const float* __restrict__ pw, const float* __restrict__ pb,
                              float* __restrict__ gridc)
{
    int t = blockIdx.x * blockDim.x + threadIdx.x;
    const int total = 2 * 8 * 256 * 12;
    if (t >= total) return;
    int c = t % 12;
    int p = (t / 12) & 255;
    int z = (t / 3072) & 7;
    int n = t / 24576;
    int co = c * 8 + z;

    const float4* lp = (const float4*)(loc + ((size_t)n * 256 + p) * 64);
    const float4* gp = (const float4*)(glob + (size_t)n * 64);
    const float4* wp = (const float4*)(pw + (size_t)co * 64);
    float acc = pb[co];
    #pragma unroll
    for (int i = 0; i < 16; ++i) {
        float4 l = lp[i], g = gp[i], w = wp[i];
        acc = fmaf(fmaxf(l.x + g.x, 0.0f), w.x, acc);
        acc = fmaf(fmaxf(l.y + g.y, 0.0f), w.y, acc);
        acc = fmaf(fmaxf(l.z + g.z, 0.0f), w.z, acc);
        acc = fmaf(fmaxf(l.w + g.w, 0.0f), w.w, acc);
    }
    gridc[t] = acc;
}

// ---------------------------------------------------------------------------
// Fused guide + trilinear slice + affine apply. One thread per pixel.
// Grid gathers are 3x float4 per corner (coeff-contiguous layout).
// ---------------------------------------------------------------------------
__global__ void guide_slice_apply2_k(const float* __restrict__ fullres,
                                     const float* __restrict__ gridc,
                                     const float* __restrict__ M,
                                     const float* __restrict__ Mb,
                                     const float* __restrict__ thr,
                                     const float* __restrict__ slopes,
                                     const float* __restrict__ gbias,
                                     float* __restrict__ out,
                                     int N, int H, int W)
{
    int idx = blockIdx.x * blockDim.x + threadIdx.x;
    int total = N * H * W;
    if (idx >= total) return;
    int w = idx % W;
    int h = (idx / W) % H;
    int n = idx / (W * H);

    size_t plane = (size_t)H * W;
    size_t base  = (size_t)n * 3 * plane + (size_t)h * W + w;
    float r  = fullres[base];
    float g  = fullres[base + plane];
    float bc = fullres[base + 2 * plane];

    // ---- guide ----
    float gs = 0.0f;
    #pragma unroll
    for (int j = 0; j < 3; ++j) {
        float gj = Mb[j] + r * M[j] + g * M[3 + j] + bc * M[6 + j];
        float s = 0.0f;
        #pragma unroll
        for (int k = 0; k < 16; ++k)
            s = fmaf(slopes[j * 16 + k], fmaxf(gj - thr[j * 16 + k], 0.0f), s);
        gs += s;
    }
    float guide = fminf(fmaxf(gs * (1.0f / 3.0f) + gbias[0], 0.0f), 1.0f);

    // ---- slice coords ----
    float ix = fminf(fmaxf((float)w * (16.0f / (W - 1)) - 0.5f, 0.0f), 15.0f);
    float iy = fminf(fmaxf((float)h * (16.0f / (H - 1)) - 0.5f, 0.0f), 15.0f);
    float iz = fminf(fmaxf(8.0f * guide - 0.5f, 0.0f), 7.0f);

    float x0f = floorf(ix), y0f = floorf(iy), z0f = floorf(iz);
    float wx = ix - x0f, wy = iy - y0f, wz = iz - z0f;
    int x0 = (int)x0f; int x1 = min(x0 + 1, 15);
    int y0 = (int)y0f; int y1 = min(y0 + 1, 15);
    int z0 = (int)z0f; int z1 = min(z0 + 1, 7);

    int o00 = y0 * 16 + x0, o01 = y0 * 16 + x1;
    int o10 = y1 * 16 + x0, o11 = y1 * 16 + x1;

    float4 A0 = {0.f, 0.f, 0.f, 0.f}, A1 = A0, A2 = A0;
    auto corner = [&](int z, int o, float wt) {
        const float4* p = (const float4*)(gridc + (((size_t)n * 8 + z) * 256 + o) * 12);
        float4 v0 = p[0], v1 = p[1], v2 = p[2];
        A0.x = fmaf(wt, v0.x, A0.x); A0.y = fmaf(wt, v0.y, A0.y);
        A0.z = fmaf(wt, v0.z, A0.z); A0.w = fmaf(wt, v0.w, A0.w);
        A1.x = fmaf(wt, v1.x, A1.x); A1.y = fmaf(wt, v1.y, A1.y);
        A1.z = fmaf(wt, v1.z, A1.z); A1.w = fmaf(wt, v1.w, A1.w);
        A2.x = fmaf(wt, v2.x, A2.x); A2.y = fmaf(wt, v2.y, A2.y);
        A2.z = fmaf(wt, v2.z, A2.z); A2.w = fmaf(wt, v2.w, A2.w);
    };
    float mz = 1.f - wz, my = 1.f - wy, mx = 1.f - wx;
    corner(z0, o00, mz * my * mx);
    corner(z0, o01, mz * my * wx);
    corner(z0, o10, mz * wy * mx);
    corner(z0, o11, mz * wy * wx);
    corner(z1, o00, wz * my * mx);
    corner(z1, o01, wz * my * wx);
    corner(z1, o10, wz * wy * mx);
    corner(z1, o11, wz * wy * wx);

    float rr = fmaf(r, A0.x, fmaf(g, A0.y, fmaf(bc, A0.z, A0.w)));
    float gg = fmaf(r, A1.x, fmaf(g, A1.y, fmaf(bc, A1.z, A1.w)));
    float bb = fmaf(r, A2.x, fmaf(g, A2.y, fmaf(bc, A2.z, A2.w)));

    out[base]             = rr;
    out[base + plane]     = gg;
    out[base + 2 * plane] = bb;
}

// ---------------------------------------------------------------------------
extern "C" void kernel_launch(void* const* d_in, const int* in_sizes, int n_in,
                              void* d_out, int out_size, void* d_ws, size_t ws_size,
                              hipStream_t stream)
{
    const float* lowres  = (const float*)d_in[0];
    const float* fullres = (const float*)d_in[1];
    const float* sw1 = (const float*)d_in[2];  const float* sb1 = (const float*)d_in[3];
    const float* sw2 = (const float*)d_in[4];  const float* sb2 = (const float*)d_in[5];
    const float* sw3 = (const float*)d_in[6];  const float* sb3 = (const float*)d_in[7];
    const float* sw4 = (const float*)d_in[8];  const float* sb4 = (const float*)d_in[9];
    const float* gw1 = (const float*)d_in[10]; const float* gb1 = (const float*)d_in[11];
    const float* gw2 = (const float*)d_in[12]; const float* gb2 = (const float*)d_in[13];
    const float* fw3 = (const float*)d_in[14]; const float* fb3 = (const float*)d_in[15];
    const float* fw4 = (const float*)d_in[16]; const float* fb4 = (const float*)d_in[17];
    const float* fw5 = (const float*)d_in[18]; const float* fb5 = (const float*)d_in[19];
    const float* lw1 = (const float*)d_in[20]; const float* lb1 = (const float*)d_in[21];
    const float* lw2 = (const float*)d_in[22];
    const float* pw  = (const float*)d_in[23]; const float* pb  = (const float*)d_in[24];
    const float* M   = (const float*)d_in[25]; const float* Mb  = (const float*)d_in[26];
    const float* thr = (const float*)d_in[27]; const float* slp = (const float*)d_in[28];
    const float* gbias = (const float*)d_in[29];

    const int N = 2, H = 1024, W = 1024;

    float* ws    = (float*)d_ws;
    float* x1    = ws;             // HWC [2][128][128][8]  = 262144
    float* x2    = x1 + 262144;    // HWC [2][64][64][16]   = 131072
    float* x3    = x2 + 131072;    // HWC [2][32][32][32]   = 65536
    float* splat = x3 + 65536;     // HWC [2][16][16][64]   = 32768
    float* g1    = splat + 32768;  // HWC [2][8][8][64]     = 8192
    float* g2    = g1 + 8192;      // HWC [2][4][4][64]     = 2048
    float* glob  = g2 + 2048;      // [2][64]               = 128
    float* l1    = glob + 128;     // HWC [2][16][16][64]   = 32768
    float* loc   = l1 + 32768;     // HWC [2][16][16][64]   = 32768
    float* gridc = loc + 32768;    // [2][8][16][16][12]    = 49152

    const int B = 256;
    auto wblk = [](int total_out, int opw) {
        int waves = (total_out + opw - 1) / opw;
        return (waves * 64 + 255) / 256;
    };

    // low-res coefficient CNN (all HWC after conv1)
    conv1_hwc_k<<<(2*128*128*8)/B, B, 0, stream>>>(lowres, sw1, sb1, x1);
    convw_hwc_k<8><<<wblk(2*64*64*16, 8), B, 0, stream>>>(x1, sw2, sb2, x2,
        N, 128, 128, 16, 64, 64, 2, 1);
    convw_hwc_k<16><<<wblk(2*32*32*32, 4), B, 0, stream>>>(x2, sw3, sb3, x3,
        N, 64, 64, 32, 32, 32, 2, 1);
    convw_hwc_k<32><<<wblk(2*16*16*64, 2), B, 0, stream>>>(x3, sw4, sb4, splat,
        N, 32, 32, 64, 16, 16, 2, 1);
    convw_hwc_k<64><<<wblk(2*8*8*64, 1), B, 0, stream>>>(splat, gw1, gb1, g1,
        N, 16, 16, 64, 8, 8, 2, 1);
    convw_hwc_k<64><<<wblk(2*4*4*64, 1), B, 0, stream>>>(g1, gw2, gb2, g2,
        N, 8, 8, 64, 4, 4, 2, 1);

    // fused FC head (fc3+fc4+fc5), one block per batch item
    fc_head_k<<<N, 1024, 0, stream>>>(g2, fw3, fb3, fw4, fb4, fw5, fb5, glob);

    // local path
    convw_hwc_k<64><<<wblk(2*16*16*64, 1), B, 0, stream>>>(splat, lw1, lb1, l1,
        N, 16, 16, 64, 16, 16, 1, 1);
    convw_hwc_k<64><<<wblk(2*16*16*64, 1), B, 0, stream>>>(l1, lw2, nullptr, loc,
        N, 16, 16, 64, 16, 16, 1, 0);

    // fusion + pointwise -> cell-major bilateral grid
    fusion_grid_k<<<(2*8*256*12 + B - 1)/B, B, 0, stream>>>(loc, glob, pw, pb, gridc);

    // full-res guide + slice + apply
    guide_slice_apply2_k<<<(N*H*W)/B, B, 0, stream>>>(fullres, gridc, M, Mb,
        thr, slp, gbias, (float*)d_out, N, H, W);
}

// Round 4
// 136.695 us; speedup vs baseline: 1.8767x; 1.8767x over previous
//
#include <hip/hip_runtime.h>

// ===========================================================================
// Layouts: the low-res chain uses HWC (channel-last) so that wave-convs with
// lane=channel get fully coalesced loads. The bilateral grid is stored
// cell-major [N][8][16][16][12] so the slice gathers 12 coeffs as 3x float4.
// ===========================================================================

// ---------------------------------------------------------------------------
// conv1: lowres CHW [N,3,256,256] -> x1 HWC [N,128,128,8], stride 2, relu.
// ---------------------------------------------------------------------------
__global__ void conv1_hwc_k(const float* __restrict__ in, const float* __restrict__ w,
                            const float* __restrict__ b, float* __restrict__ out)
{
    int t = blockIdx.x * blockDim.x + threadIdx.x;
    const int total = 2 * 128 * 128 * 8;
    if (t >= total) return;
    int co = t & 7;
    int ow = (t >> 3) & 127;
    int oh = (t >> 10) & 127;
    int n  = t >> 17;

    float acc = b[co];
    #pragma unroll
    for (int ci = 0; ci < 3; ++ci) {
        const float* ib = in + ((size_t)(n * 3 + ci)) * 65536;
        const float* wb = w + ((size_t)co * 3 + ci) * 9;
        #pragma unroll
        for (int kh = 0; kh < 3; ++kh) {
            int ih = oh * 2 - 1 + kh;
            if (ih < 0 || ih >= 256) continue;
            #pragma unroll
            for (int kw = 0; kw < 3; ++kw) {
                int iw = ow * 2 - 1 + kw;
                if (iw < 0 || iw >= 256) continue;
                acc = fmaf(ib[ih * 256 + iw], wb[kh * 3 + kw], acc);
            }
        }
    }
    out[t] = fmaxf(acc, 0.0f);
}

// ---------------------------------------------------------------------------
// Wave conv, HWC in/out. Each 64-lane wave computes OPW=64/CIN consecutive
// outputs (same pixel, consecutive co); lane = input channel.
// ---------------------------------------------------------------------------
template <int CIN>
__global__ void convw_hwc_k(const float* __restrict__ in, const float* __restrict__ w,
                            const float* __restrict__ b, float* __restrict__ out,
                            int N, int Hin, int Win, int Cout, int Hout, int Wout,
                            int stride, int do_relu)
{
    constexpr int OPW = 64 / CIN;
    int lane = threadIdx.x & 63;
    int wid  = (blockIdx.x * blockDim.x + threadIdx.x) >> 6;
    int sub  = lane / CIN;
    int cl   = lane % CIN;
    int o    = wid * OPW + sub;
    int total = N * Hout * Wout * Cout;

    float acc = 0.0f;
    if (o < total) {
        int co  = o % Cout;
        int pix = o / Cout;
        int ow  = pix % Wout;
        int oh  = (pix / Wout) % Hout;
        int n   = pix / (Wout * Hout);
        const float* wb = w + ((size_t)co * CIN + cl) * 9;
        #pragma unroll
        for (int kh = 0; kh < 3; ++kh) {
            int ih = oh * stride - 1 + kh;
            if (ih < 0 || ih >= Hin) continue;
            const float* ib = in + (((size_t)(n * Hin + ih)) * Win) * CIN + cl;
            #pragma unroll
            for (int kw = 0; kw < 3; ++kw) {
                int iw = ow * stride - 1 + kw;
                if (iw < 0 || iw >= Win) continue;
                acc = fmaf(ib[(size_t)iw * CIN], wb[kh * 3 + kw], acc);
            }
        }
    }
    #pragma unroll
    for (int off = CIN / 2; off >= 1; off >>= 1)
        acc += __shfl_xor(acc, off, 64);

    if (o < total && cl == 0) {
        if (b) acc += b[o % Cout];
        if (do_relu) acc = fmaxf(acc, 0.0f);
        out[o] = acc;
    }
}

// ---------------------------------------------------------------------------
// fc3: wave per output; input g2 is HWC [N][16][64], weights are CHW-flat
// (j = c*16 + p) so permute the input index (g2 is 4KB, L1-hot).
// ---------------------------------------------------------------------------
__global__ void fc3_wave_k(const float* __restrict__ g2, const float* __restrict__ w,
                           const float* __restrict__ b, float* __restrict__ out,
                           int N)
{
    int lane = threadIdx.x & 63;
    int wid  = (blockIdx.x * blockDim.x + threadIdx.x) >> 6;
    if (wid >= N * 256) return;
    int o = wid % 256;
    int n = wid / 256;
    const float* g2n = g2 + (size_t)n * 1024;
    const float* wb  = w + (size_t)o * 1024;
    float acc = 0.0f;
    #pragma unroll
    for (int i = 0; i < 16; ++i) {
        int j = lane + i * 64;
        acc = fmaf(g2n[(j & 15) * 64 + (j >> 4)], wb[j], acc);
    }
    #pragma unroll
    for (int off = 32; off >= 1; off >>= 1) acc += __shfl_xor(acc, off, 64);
    if (lane == 0) out[wid] = fmaxf(acc + b[o], 0.0f);
}

// ---------------------------------------------------------------------------
// Generic wave-per-output FC.
// ---------------------------------------------------------------------------
__global__ void fc_wave_k(const float* __restrict__ in, const float* __restrict__ w,
                          const float* __restrict__ b, float* __restrict__ out,
                          int N, int IN, int OUT, int do_relu)
{
    int lane = threadIdx.x & 63;
    int wid  = (blockIdx.x * blockDim.x + threadIdx.x) >> 6;
    if (wid >= N * OUT) return;
    int o = wid % OUT;
    int n = wid / OUT;
    const float* ib = in + (size_t)n * IN;
    const float* wb = w + (size_t)o * IN;
    float acc = 0.0f;
    for (int i = lane; i < IN; i += 64)
        acc = fmaf(ib[i], wb[i], acc);
    #pragma unroll
    for (int off = 32; off >= 1; off >>= 1) acc += __shfl_xor(acc, off, 64);
    if (lane == 0) {
        acc += b[o];
        if (do_relu) acc = fmaxf(acc, 0.0f);
        out[wid] = acc;
    }
}

// ---------------------------------------------------------------------------
// fusion = relu(loc + glob); grid = pw @ fusion + pb, written CELL-MAJOR:
// gridc[((n*8+z)*256 + y*16+x)*12 + c] where original co = c*8+z. loc is HWC.
// ---------------------------------------------------------------------------
__global__ void fusion_grid_k(const float* __restrict__ loc, const float* __restrict__ glob,
                              const float* __restrict__ pw, const float* __restrict__ pb,
                              float* __restrict__ gridc)
{
    int t = blockIdx.x * blockDim.x + threadIdx.x;
    const int total = 2 * 8 * 256 * 12;
    if (t >= total) return;
    int c = t % 12;
    int p = (t / 12) & 255;
    int z = (t / 3072) & 7;
    int n = t / 24576;
    int co = c * 8 + z;

    const float4* lp = (const float4*)(loc + ((size_t)n * 256 + p) * 64);
    const float4* gp = (const float4*)(glob + (size_t)n * 64);
    const float4* wp = (const float4*)(pw + (size_t)co * 64);
    float acc = pb[co];
    #pragma unroll
    for (int i = 0; i < 16; ++i) {
        float4 l = lp[i], g = gp[i], w = wp[i];
        acc = fmaf(fmaxf(l.x + g.x, 0.0f), w.x, acc);
        acc = fmaf(fmaxf(l.y + g.y, 0.0f), w.y, acc);
        acc = fmaf(fmaxf(l.z + g.z, 0.0f), w.z, acc);
        acc = fmaf(fmaxf(l.w + g.w, 0.0f), w.w, acc);
    }
    gridc[t] = acc;
}

// ---------------------------------------------------------------------------
// Fused guide + trilinear slice + affine apply. One thread per pixel.
// ---------------------------------------------------------------------------
__global__ void guide_slice_apply2_k(const float* __restrict__ fullres,
                                     const float* __restrict__ gridc,
                                     const float* __restrict__ M,
                                     const float* __restrict__ Mb,
                                     const float* __restrict__ thr,
                                     const float* __restrict__ slopes,
                                     const float* __restrict__ gbias,
                                     float* __restrict__ out,
                                     int N, int H, int W)
{
    int idx = blockIdx.x * blockDim.x + threadIdx.x;
    int total = N * H * W;
    if (idx >= total) return;
    int w = idx % W;
    int h = (idx / W) % H;
    int n = idx / (W * H);

    size_t plane = (size_t)H * W;
    size_t base  = (size_t)n * 3 * plane + (size_t)h * W + w;
    float r  = fullres[base];
    float g  = fullres[base + plane];
    float bc = fullres[base + 2 * plane];

    float gs = 0.0f;
    #pragma unroll
    for (int j = 0; j < 3; ++j) {
        float gj = Mb[j] + r * M[j] + g * M[3 + j] + bc * M[6 + j];
        float s = 0.0f;
        #pragma unroll
        for (int k = 0; k < 16; ++k)
            s = fmaf(slopes[j * 16 + k], fmaxf(gj - thr[j * 16 + k], 0.0f), s);
        gs += s;
    }
    float guide = fminf(fmaxf(gs * (1.0f / 3.0f) + gbias[0], 0.0f), 1.0f);

    float ix = fminf(fmaxf((float)w * (16.0f / (W - 1)) - 0.5f, 0.0f), 15.0f);
    float iy = fminf(fmaxf((float)h * (16.0f / (H - 1)) - 0.5f, 0.0f), 15.0f);
    float iz = fminf(fmaxf(8.0f * guide - 0.5f, 0.0f), 7.0f);

    float x0f = floorf(ix), y0f = floorf(iy), z0f = floorf(iz);
    float wx = ix - x0f, wy = iy - y0f, wz = iz - z0f;
    int x0 = (int)x0f; int x1 = min(x0 + 1, 15);
    int y0 = (int)y0f; int y1 = min(y0 + 1, 15);
    int z0 = (int)z0f; int z1 = min(z0 + 1, 7);

    int o00 = y0 * 16 + x0, o01 = y0 * 16 + x1;
    int o10 = y1 * 16 + x0, o11 = y1 * 16 + x1;

    float4 A0 = {0.f, 0.f, 0.f, 0.f}, A1 = A0, A2 = A0;
    auto corner = [&](int z, int o, float wt) {
        const float4* p = (const float4*)(gridc + (((size_t)n * 8 + z) * 256 + o) * 12);
        float4 v0 = p[0], v1 = p[1], v2 = p[2];
        A0.x = fmaf(wt, v0.x, A0.x); A0.y = fmaf(wt, v0.y, A0.y);
        A0.z = fmaf(wt, v0.z, A0.z); A0.w = fmaf(wt, v0.w, A0.w);
        A1.x = fmaf(wt, v1.x, A1.x); A1.y = fmaf(wt, v1.y, A1.y);
        A1.z = fmaf(wt, v1.z, A1.z); A1.w = fmaf(wt, v1.w, A1.w);
        A2.x = fmaf(wt, v2.x, A2.x); A2.y = fmaf(wt, v2.y, A2.y);
        A2.z = fmaf(wt, v2.z, A2.z); A2.w = fmaf(wt, v2.w, A2.w);
    };
    float mz = 1.f - wz, my = 1.f - wy, mx = 1.f - wx;
    corner(z0, o00, mz * my * mx);
    corner(z0, o01, mz * my * wx);
    corner(z0, o10, mz * wy * mx);
    corner(z0, o11, mz * wy * wx);
    corner(z1, o00, wz * my * mx);
    corner(z1, o01, wz * my * wx);
    corner(z1, o10, wz * wy * mx);
    corner(z1, o11, wz * wy * wx);

    float rr = fmaf(r, A0.x, fmaf(g, A0.y, fmaf(bc, A0.z, A0.w)));
    float gg = fmaf(r, A1.x, fmaf(g, A1.y, fmaf(bc, A1.z, A1.w)));
    float bb = fmaf(r, A2.x, fmaf(g, A2.y, fmaf(bc, A2.z, A2.w)));

    out[base]             = rr;
    out[base + plane]     = gg;
    out[base + 2 * plane] = bb;
}

// ---------------------------------------------------------------------------
extern "C" void kernel_launch(void* const* d_in, const int* in_sizes, int n_in,
                              void* d_out, int out_size, void* d_ws, size_t ws_size,
                              hipStream_t stream)
{
    const float* lowres  = (const float*)d_in[0];
    const float* fullres = (const float*)d_in[1];
    const float* sw1 = (const float*)d_in[2];  const float* sb1 = (const float*)d_in[3];
    const float* sw2 = (const float*)d_in[4];  const float* sb2 = (const float*)d_in[5];
    const float* sw3 = (const float*)d_in[6];  const float* sb3 = (const float*)d_in[7];
    const float* sw4 = (const float*)d_in[8];  const float* sb4 = (const float*)d_in[9];
    const float* gw1 = (const float*)d_in[10]; const float* gb1 = (const float*)d_in[11];
    const float* gw2 = (const float*)d_in[12]; const float* gb2 = (const float*)d_in[13];
    const float* fw3 = (const float*)d_in[14]; const float* fb3 = (const float*)d_in[15];
    const float* fw4 = (const float*)d_in[16]; const float* fb4 = (const float*)d_in[17];
    const float* fw5 = (const float*)d_in[18]; const float* fb5 = (const float*)d_in[19];
    const float* lw1 = (const float*)d_in[20]; const float* lb1 = (const float*)d_in[21];
    const float* lw2 = (const float*)d_in[22];
    const float* pw  = (const float*)d_in[23]; const float* pb  = (const float*)d_in[24];
    const float* M   = (const float*)d_in[25]; const float* Mb  = (const float*)d_in[26];
    const float* thr = (const float*)d_in[27]; const float* slp = (const float*)d_in[28];
    const float* gbias = (const float*)d_in[29];

    const int N = 2, H = 1024, W = 1024;

    float* ws    = (float*)d_ws;
    float* x1    = ws;             // HWC [2][128][128][8]  = 262144
    float* x2    = x1 + 262144;    // HWC [2][64][64][16]   = 131072
    float* x3    = x2 + 131072;    // HWC [2][32][32][32]   = 65536
    float* splat = x3 + 65536;     // HWC [2][16][16][64]   = 32768
    float* g1    = splat + 32768;  // HWC [2][8][8][64]     = 8192
    float* g2    = g1 + 8192;      // HWC [2][4][4][64]     = 2048
    float* fc3o  = g2 + 2048;      // [2][256]              = 512
    float* fc4o  = fc3o + 512;     // [2][128]              = 256
    float* glob  = fc4o + 256;     // [2][64]               = 128
    float* l1    = glob + 128;     // HWC [2][16][16][64]   = 32768
    float* loc   = l1 + 32768;     // HWC [2][16][16][64]   = 32768
    float* gridc = loc + 32768;    // [2][8][16][16][12]    = 49152

    const int B = 256;
    auto wblk = [](int total_out, int opw) {
        int waves = (total_out + opw - 1) / opw;
        return (waves * 64 + 255) / 256;
    };

    // low-res coefficient CNN (all HWC after conv1)
    conv1_hwc_k<<<(2*128*128*8)/B, B, 0, stream>>>(lowres, sw1, sb1, x1);
    convw_hwc_k<8><<<wblk(2*64*64*16, 8), B, 0, stream>>>(x1, sw2, sb2, x2,
        N, 128, 128, 16, 64, 64, 2, 1);
    convw_hwc_k<16><<<wblk(2*32*32*32, 4), B, 0, stream>>>(x2, sw3, sb3, x3,
        N, 64, 64, 32, 32, 32, 2, 1);
    convw_hwc_k<32><<<wblk(2*16*16*64, 2), B, 0, stream>>>(x3, sw4, sb4, splat,
        N, 32, 32, 64, 16, 16, 2, 1);
    convw_hwc_k<64><<<wblk(2*8*8*64, 1), B, 0, stream>>>(splat, gw1, gb1, g1,
        N, 16, 16, 64, 8, 8, 2, 1);
    convw_hwc_k<64><<<wblk(2*4*4*64, 1), B, 0, stream>>>(g1, gw2, gb2, g2,
        N, 8, 8, 64, 4, 4, 2, 1);

    // global FC path (wave-per-output, fully parallel)
    fc3_wave_k<<<wblk(N*256, 1), B, 0, stream>>>(g2, fw3, fb3, fc3o, N);
    fc_wave_k<<<wblk(N*128, 1), B, 0, stream>>>(fc3o, fw4, fb4, fc4o, N, 256, 128, 1);
    fc_wave_k<<<wblk(N*64, 1), B, 0, stream>>>(fc4o, fw5, fb5, glob, N, 128, 64, 0);

    // local path
    convw_hwc_k<64><<<wblk(2*16*16*64, 1), B, 0, stream>>>(splat, lw1, lb1, l1,
        N, 16, 16, 64, 16, 16, 1, 1);
    convw_hwc_k<64><<<wblk(2*16*16*64, 1), B, 0, stream>>>(l1, lw2, nullptr, loc,
        N, 16, 16, 64, 16, 16, 1, 0);

    // fusion + pointwise -> cell-major bilateral grid
    fusion_grid_k<<<(2*8*256*12 + B - 1)/B, B, 0, stream>>>(loc, glob, pw, pb, gridc);

    // full-res guide + slice + apply
    guide_slice_apply2_k<<<(N*H*W)/B, B, 0, stream>>>(fullres, gridc, M, Mb,
        thr, slp, gbias, (float*)d_out, N, H, W);
}

// Round 5
// 135.891 us; speedup vs baseline: 1.8878x; 1.0059x over previous
//
#include <hip/hip_runtime.h>

// ===========================================================================
// Layouts: low-res chain is HWC (channel-last) so lane=channel wave-convs get
// coalesced 256B segment loads. Bilateral grid is cell-major
// [N][8][16][16][12] so the slice gathers 12 coeffs as 3x float4.
// Graph has 10 nodes: conv1,conv2,conv3,conv4,(l1||g1),(loc||g2),fc3,fc45,
// fusion,slice. Independent stages share a launch via wave-role split;
// sequential small-tensor fusion is avoided (single-CU = 307 GMAC/s only).
// ===========================================================================

// ---------------------------------------------------------------------------
// conv1: lowres CHW [N,3,256,256] -> x1 HWC [N,128,128,8], stride 2, relu.
// ---------------------------------------------------------------------------
__global__ void conv1_hwc_k(const float* __restrict__ in, const float* __restrict__ w,
                            const float* __restrict__ b, float* __restrict__ out)
{
    int t = blockIdx.x * blockDim.x + threadIdx.x;
    const int total = 2 * 128 * 128 * 8;
    if (t >= total) return;
    int co = t & 7;
    int ow = (t >> 3) & 127;
    int oh = (t >> 10) & 127;
    int n  = t >> 17;

    float acc = b[co];
    #pragma unroll
    for (int ci = 0; ci < 3; ++ci) {
        const float* ib = in + ((size_t)(n * 3 + ci)) * 65536;
        const float* wb = w + ((size_t)co * 3 + ci) * 9;
        #pragma unroll
        for (int kh = 0; kh < 3; ++kh) {
            int ih = oh * 2 - 1 + kh;
            if (ih < 0 || ih >= 256) continue;
            #pragma unroll
            for (int kw = 0; kw < 3; ++kw) {
                int iw = ow * 2 - 1 + kw;
                if (iw < 0 || iw >= 256) continue;
                acc = fmaf(ib[ih * 256 + iw], wb[kh * 3 + kw], acc);
            }
        }
    }
    out[t] = fmaxf(acc, 0.0f);
}

// ---------------------------------------------------------------------------
// Wave conv, HWC in/out, lane = input channel, subgroup shuffle-reduce.
// ---------------------------------------------------------------------------
template <int CIN>
__global__ void convw_hwc_k(const float* __restrict__ in, const float* __restrict__ w,
                            const float* __restrict__ b, float* __restrict__ out,
                            int N, int Hin, int Win, int Cout, int Hout, int Wout,
                            int stride, int do_relu)
{
    constexpr int OPW = 64 / CIN;
    int lane = threadIdx.x & 63;
    int wid  = (blockIdx.x * blockDim.x + threadIdx.x) >> 6;
    int sub  = lane / CIN;
    int cl   = lane % CIN;
    int o    = wid * OPW + sub;
    int total = N * Hout * Wout * Cout;

    float acc = 0.0f;
    if (o < total) {
        int co  = o % Cout;
        int pix = o / Cout;
        int ow  = pix % Wout;
        int oh  = (pix / Wout) % Hout;
        int n   = pix / (Wout * Hout);
        const float* wb = w + ((size_t)co * CIN + cl) * 9;
        #pragma unroll
        for (int kh = 0; kh < 3; ++kh) {
            int ih = oh * stride - 1 + kh;
            if (ih < 0 || ih >= Hin) continue;
            const float* ib = in + (((size_t)(n * Hin + ih)) * Win) * CIN + cl;
            #pragma unroll
            for (int kw = 0; kw < 3; ++kw) {
                int iw = ow * stride - 1 + kw;
                if (iw < 0 || iw >= Win) continue;
                acc = fmaf(ib[(size_t)iw * CIN], wb[kh * 3 + kw], acc);
            }
        }
    }
    #pragma unroll
    for (int off = CIN / 2; off >= 1; off >>= 1)
        acc += __shfl_xor(acc, off, 64);

    if (o < total && cl == 0) {
        if (b) acc += b[o % Cout];
        if (do_relu) acc = fmaxf(acc, 0.0f);
        out[o] = acc;
    }
}

// ---------------------------------------------------------------------------
// One CIN=64 wave-conv output (lane = input channel). in/out are n-local HWC.
// ---------------------------------------------------------------------------
__device__ __forceinline__ void convw64_one(const float* __restrict__ in,
                                            const float* __restrict__ wgt,
                                            const float* __restrict__ bias,
                                            float* __restrict__ out,
                                            int o, int Hin, int Win, int Wout,
                                            int stride, bool relu, int lane)
{
    int co  = o & 63;
    int pix = o >> 6;
    int ow  = pix % Wout;
    int oh  = pix / Wout;
    const float* wb = wgt + ((size_t)co * 64 + lane) * 9;
    float acc = 0.0f;
    #pragma unroll
    for (int kh = 0; kh < 3; ++kh) {
        int ih = oh * stride - 1 + kh;
        if (ih < 0 || ih >= Hin) continue;
        const float* ib = in + ((size_t)ih * Win) * 64 + lane;
        #pragma unroll
        for (int kw = 0; kw < 3; ++kw) {
            int iw = ow * stride - 1 + kw;
            if (iw < 0 || iw >= Win) continue;
            acc = fmaf(ib[(size_t)iw * 64], wb[kh * 3 + kw], acc);
        }
    }
    #pragma unroll
    for (int off = 32; off >= 1; off >>= 1)
        acc += __shfl_xor(acc, off, 64);
    if (lane == 0) {
        if (bias) acc += bias[co];
        if (relu) acc = fmaxf(acc, 0.0f);
        out[o] = acc;
    }
}

// ---------------------------------------------------------------------------
// l1 || g1 (both read splat; independent). Wave-role split, full width.
// l1: 16x16 s1 relu (32768 wave-outputs); g1: ->8x8 s2 relu (8192).
// ---------------------------------------------------------------------------
__global__ void l1_g1_k(const float* __restrict__ splat,
                        const float* __restrict__ lw1, const float* __restrict__ lb1,
                        const float* __restrict__ gw1, const float* __restrict__ gb1,
                        float* __restrict__ l1, float* __restrict__ g1)
{
    int lane = threadIdx.x & 63;
    int W = (blockIdx.x * blockDim.x + threadIdx.x) >> 6;
    if (W < 32768) {
        int n = W >> 14, o = W & 16383;
        convw64_one(splat + (size_t)n * 16384, lw1, lb1, l1 + (size_t)n * 16384,
                    o, 16, 16, 16, 1, true, lane);
    } else {
        int W2 = W - 32768;
        if (W2 >= 8192) return;
        int n = W2 >> 12, o = W2 & 4095;
        convw64_one(splat + (size_t)n * 16384, gw1, gb1, g1 + (size_t)n * 4096,
                    o, 16, 16, 8, 2, true, lane);
    }
}

// ---------------------------------------------------------------------------
// loc || g2. loc: conv(l1), no bias/relu (32768); g2: 8x8->4x4 s2 relu (2048).
// ---------------------------------------------------------------------------
__global__ void loc_g2_k(const float* __restrict__ l1, const float* __restrict__ lw2,
                         const float* __restrict__ g1, const float* __restrict__ gw2,
                         const float* __restrict__ gb2,
                         float* __restrict__ loc, float* __restrict__ g2)
{
    int lane = threadIdx.x & 63;
    int W = (blockIdx.x * blockDim.x + threadIdx.x) >> 6;
    if (W < 32768) {
        int n = W >> 14, o = W & 16383;
        convw64_one(l1 + (size_t)n * 16384, lw2, nullptr, loc + (size_t)n * 16384,
                    o, 16, 16, 16, 1, false, lane);
    } else {
        int W2 = W - 32768;
        if (W2 >= 2048) return;
        int n = W2 >> 10, o = W2 & 1023;
        convw64_one(g1 + (size_t)n * 4096, gw2, gb2, g2 + (size_t)n * 1024,
                    o, 8, 8, 4, 2, true, lane);
    }
}

// ---------------------------------------------------------------------------
// fc3: wave per output; g2 is HWC [N][16][64]; weights CHW-flat (j=c*16+p).
// ---------------------------------------------------------------------------
__global__ void fc3_wave_k(const float* __restrict__ g2, const float* __restrict__ w,
                           const float* __restrict__ b, float* __restrict__ out,
                           int N)
{
    int lane = threadIdx.x & 63;
    int wid  = (blockIdx.x * blockDim.x + threadIdx.x) >> 6;
    if (wid >= N * 256) return;
    int o = wid % 256;
    int n = wid / 256;
    const float* g2n = g2 + (size_t)n * 1024;
    const float* wb  = w + (size_t)o * 1024;
    float acc = 0.0f;
    #pragma unroll
    for (int i = 0; i < 16; ++i) {
        int j = lane + i * 64;
        acc = fmaf(g2n[(j & 15) * 64 + (j >> 4)], wb[j], acc);
    }
    #pragma unroll
    for (int off = 32; off >= 1; off >>= 1) acc += __shfl_xor(acc, off, 64);
    if (lane == 0) out[wid] = fmaxf(acc + b[o], 0.0f);
}

// ---------------------------------------------------------------------------
// fc4+fc5 fused: one 1024-thread block per batch item (tiny compute; weights
// are L3-hot). fc4 results staged in LDS.
// ---------------------------------------------------------------------------
__global__ void fc45_k(const float* __restrict__ fc3o,
                       const float* __restrict__ fw4, const float* __restrict__ fb4,
                       const float* __restrict__ fw5, const float* __restrict__ fb5,
                       float* __restrict__ glob)
{
    __shared__ float s4[128];
    int n    = blockIdx.x;
    int lane = threadIdx.x & 63;
    int wv   = threadIdx.x >> 6;          // 16 waves
    const float* in = fc3o + (size_t)n * 256;

    #pragma unroll
    for (int k = 0; k < 8; ++k) {
        int o = wv * 8 + k;
        const float* wb = fw4 + (size_t)o * 256;
        float acc = 0.0f;
        #pragma unroll
        for (int j = 0; j < 4; ++j)
            acc = fmaf(in[lane + j * 64], wb[lane + j * 64], acc);
        #pragma unroll
        for (int off = 32; off >= 1; off >>= 1) acc += __shfl_xor(acc, off, 64);
        if (lane == 0) s4[o] = fmaxf(acc + fb4[o], 0.0f);
    }
    __syncthreads();
    #pragma unroll
    for (int k = 0; k < 4; ++k) {
        int o = wv * 4 + k;
        const float* wb = fw5 + (size_t)o * 128;
        float acc = 0.0f;
        #pragma unroll
        for (int j = 0; j < 2; ++j)
            acc = fmaf(s4[lane + j * 64], wb[lane + j * 64], acc);
        #pragma unroll
        for (int off = 32; off >= 1; off >>= 1) acc += __shfl_xor(acc, off, 64);
        if (lane == 0) glob[(size_t)n * 64 + o] = acc + fb5[o];
    }
}

// ---------------------------------------------------------------------------
// fusion = relu(loc + glob); grid = pw @ fusion + pb, cell-major out:
// gridc[((n*8+z)*256 + y*16+x)*12 + c], original co = c*8+z. loc is HWC.
// ---------------------------------------------------------------------------
__global__ void fusion_grid_k(const float* __restrict__ loc, const float* __restrict__ glob,
                              const float* __restrict__ pw, const float* __restrict__ pb,
                              float* __restrict__ gridc)
{
    int t = blockIdx.x * blockDim.x + threadIdx.x;
    const int total = 2 * 8 * 256 * 12;
    if (t >= total) return;
    int c = t % 12;
    int p = (t / 12) & 255;
    int z = (t / 3072) & 7;
    int n = t / 24576;
    int co = c * 8 + z;

    const float4* lp = (const float4*)(loc + ((size_t)n * 256 + p) * 64);
    const float4* gp = (const float4*)(glob + (size_t)n * 64);
    const float4* wp = (const float4*)(pw + (size_t)co * 64);
    float acc = pb[co];
    #pragma unroll
    for (int i = 0; i < 16; ++i) {
        float4 l = lp[i], g = gp[i], w = wp[i];
        acc = fmaf(fmaxf(l.x + g.x, 0.0f), w.x, acc);
        acc = fmaf(fmaxf(l.y + g.y, 0.0f), w.y, acc);
        acc = fmaf(fmaxf(l.z + g.z, 0.0f), w.z, acc);
        acc = fmaf(fmaxf(l.w + g.w, 0.0f), w.w, acc);
    }
    gridc[t] = acc;
}

// ---------------------------------------------------------------------------
// Fused guide + trilinear slice + affine apply: 4 consecutive pixels/thread,
// float4 plane I/O. Grid gathers are 3x float4 per corner (L1-broadcast:
// ~64x64 pixels share a grid cell).
// ---------------------------------------------------------------------------
__global__ void guide_slice_apply4_k(const float* __restrict__ fullres,
                                     const float* __restrict__ gridc,
                                     const float* __restrict__ M,
                                     const float* __restrict__ Mb,
                                     const float* __restrict__ thr,
                                     const float* __restrict__ slopes,
                                     const float* __restrict__ gbias,
                                     float* __restrict__ out)
{
    const int W = 1024, H = 1024;
    int t = blockIdx.x * blockDim.x + threadIdx.x;   // 2*1024*256 groups
    int gx = t & 255;           // group of 4 pixels in row
    int h  = (t >> 8) & 1023;
    int n  = t >> 18;
    int w0 = gx * 4;

    size_t plane = (size_t)H * W;
    size_t base  = (size_t)n * 3 * plane + (size_t)h * W + w0;
    float4 R  = *(const float4*)&fullres[base];
    float4 G  = *(const float4*)&fullres[base + plane];
    float4 Bc = *(const float4*)&fullres[base + 2 * plane];

    // y coords shared across the 4 pixels
    float iy = fminf(fmaxf((float)h * (16.0f / (H - 1)) - 0.5f, 0.0f), 15.0f);
    float y0f = floorf(iy);
    float wy  = iy - y0f;
    int y0 = (int)y0f, y1 = min(y0 + 1, 15);

    float4 RR, GG, BB;
    float* rr = &RR.x; float* gg = &GG.x; float* bb = &BB.x;
    const float* rp = &R.x; const float* gp = &G.x; const float* bp = &Bc.x;

    #pragma unroll
    for (int p = 0; p < 4; ++p) {
        float r = rp[p], g = gp[p], bc = bp[p];
        int w = w0 + p;

        // ---- guide ----
        float gs = 0.0f;
        #pragma unroll
        for (int j = 0; j < 3; ++j) {
            float gj = Mb[j] + r * M[j] + g * M[3 + j] + bc * M[6 + j];
            float s = 0.0f;
            #pragma unroll
            for (int k = 0; k < 16; ++k)
                s = fmaf(slopes[j * 16 + k], fmaxf(gj - thr[j * 16 + k], 0.0f), s);
            gs += s;
        }
        float guide = fminf(fmaxf(gs * (1.0f / 3.0f) + gbias[0], 0.0f), 1.0f);

        // ---- coords ----
        float ix = fminf(fmaxf((float)w * (16.0f / (W - 1)) - 0.5f, 0.0f), 15.0f);
        float iz = fminf(fmaxf(8.0f * guide - 0.5f, 0.0f), 7.0f);
        float x0f = floorf(ix), z0f = floorf(iz);
        float wx = ix - x0f, wz = iz - z0f;
        int x0 = (int)x0f; int x1 = min(x0 + 1, 15);
        int z0 = (int)z0f; int z1 = min(z0 + 1, 7);

        int o00 = y0 * 16 + x0, o01 = y0 * 16 + x1;
        int o10 = y1 * 16 + x0, o11 = y1 * 16 + x1;

        float4 A0 = {0.f, 0.f, 0.f, 0.f}, A1 = A0, A2 = A0;
        auto corner = [&](int z, int o, float wt) {
            const float4* q = (const float4*)(gridc + (((size_t)n * 8 + z) * 256 + o) * 12);
            float4 v0 = q[0], v1 = q[1], v2 = q[2];
            A0.x = fmaf(wt, v0.x, A0.x); A0.y = fmaf(wt, v0.y, A0.y);
            A0.z = fmaf(wt, v0.z, A0.z); A0.w = fmaf(wt, v0.w, A0.w);
            A1.x = fmaf(wt, v1.x, A1.x); A1.y = fmaf(wt, v1.y, A1.y);
            A1.z = fmaf(wt, v1.z, A1.z); A1.w = fmaf(wt, v1.w, A1.w);
            A2.x = fmaf(wt, v2.x, A2.x); A2.y = fmaf(wt, v2.y, A2.y);
            A2.z = fmaf(wt, v2.z, A2.z); A2.w = fmaf(wt, v2.w, A2.w);
        };
        float mz = 1.f - wz, my = 1.f - wy, mx = 1.f - wx;
        corner(z0, o00, mz * my * mx);
        corner(z0, o01, mz * my * wx);
        corner(z0, o10, mz * wy * mx);
        corner(z0, o11, mz * wy * wx);
        corner(z1, o00, wz * my * mx);
        corner(z1, o01, wz * my * wx);
        corner(z1, o10, wz * wy * mx);
        corner(z1, o11, wz * wy * wx);

        rr[p] = fmaf(r, A0.x, fmaf(g, A0.y, fmaf(bc, A0.z, A0.w)));
        gg[p] = fmaf(r, A1.x, fmaf(g, A1.y, fmaf(bc, A1.z, A1.w)));
        bb[p] = fmaf(r, A2.x, fmaf(g, A2.y, fmaf(bc, A2.z, A2.w)));
    }

    *(float4*)&out[base]             = RR;
    *(float4*)&out[base + plane]     = GG;
    *(float4*)&out[base + 2 * plane] = BB;
}

// ---------------------------------------------------------------------------
extern "C" void kernel_launch(void* const* d_in, const int* in_sizes, int n_in,
                              void* d_out, int out_size, void* d_ws, size_t ws_size,
                              hipStream_t stream)
{
    const float* lowres  = (const float*)d_in[0];
    const float* fullres = (const float*)d_in[1];
    const float* sw1 = (const float*)d_in[2];  const float* sb1 = (const float*)d_in[3];
    const float* sw2 = (const float*)d_in[4];  const float* sb2 = (const float*)d_in[5];
    const float* sw3 = (const float*)d_in[6];  const float* sb3 = (const float*)d_in[7];
    const float* sw4 = (const float*)d_in[8];  const float* sb4 = (const float*)d_in[9];
    const float* gw1 = (const float*)d_in[10]; const float* gb1 = (const float*)d_in[11];
    const float* gw2 = (const float*)d_in[12]; const float* gb2 = (const float*)d_in[13];
    const float* fw3 = (const float*)d_in[14]; const float* fb3 = (const float*)d_in[15];
    const float* fw4 = (const float*)d_in[16]; const float* fb4 = (const float*)d_in[17];
    const float* fw5 = (const float*)d_in[18]; const float* fb5 = (const float*)d_in[19];
    const float* lw1 = (const float*)d_in[20]; const float* lb1 = (const float*)d_in[21];
    const float* lw2 = (const float*)d_in[22];
    const float* pw  = (const float*)d_in[23]; const float* pb  = (const float*)d_in[24];
    const float* M   = (const float*)d_in[25]; const float* Mb  = (const float*)d_in[26];
    const float* thr = (const float*)d_in[27]; const float* slp = (const float*)d_in[28];
    const float* gbias = (const float*)d_in[29];

    const int N = 2;

    float* ws    = (float*)d_ws;
    float* x1    = ws;             // HWC [2][128][128][8]  = 262144
    float* x2    = x1 + 262144;    // HWC [2][64][64][16]   = 131072
    float* x3    = x2 + 131072;    // HWC [2][32][32][32]   = 65536
    float* splat = x3 + 65536;     // HWC [2][16][16][64]   = 32768
    float* g1    = splat + 32768;  // HWC [2][8][8][64]     = 8192
    float* g2    = g1 + 8192;      // HWC [2][4][4][64]     = 2048
    float* fc3o  = g2 + 2048;      // [2][256]
    float* glob  = fc3o + 512;     // [2][64]
    float* l1    = glob + 128;     // HWC [2][16][16][64]   = 32768
    float* loc   = l1 + 32768;     // HWC [2][16][16][64]   = 32768
    float* gridc = loc + 32768;    // [2][8][16][16][12]    = 49152

    const int B = 256;
    auto wblk = [](int total_out, int opw) {
        int waves = (total_out + opw - 1) / opw;
        return (waves * 64 + 255) / 256;
    };

    // low-res coefficient CNN
    conv1_hwc_k<<<(2*128*128*8)/B, B, 0, stream>>>(lowres, sw1, sb1, x1);
    convw_hwc_k<8><<<wblk(2*64*64*16, 8), B, 0, stream>>>(x1, sw2, sb2, x2,
        N, 128, 128, 16, 64, 64, 2, 1);
    convw_hwc_k<16><<<wblk(2*32*32*32, 4), B, 0, stream>>>(x2, sw3, sb3, x3,
        N, 64, 64, 32, 32, 32, 2, 1);
    convw_hwc_k<32><<<wblk(2*16*16*64, 2), B, 0, stream>>>(x3, sw4, sb4, splat,
        N, 32, 32, 64, 16, 16, 2, 1);

    // l1 || g1  (32768 + 8192 wave-outputs)
    l1_g1_k<<<(40960*64)/B, B, 0, stream>>>(splat, lw1, lb1, gw1, gb1, l1, g1);
    // loc || g2 (32768 + 2048 wave-outputs)
    loc_g2_k<<<(34816*64)/B, B, 0, stream>>>(l1, lw2, g1, gw2, gb2, loc, g2);

    // global FC path
    fc3_wave_k<<<wblk(N*256, 1), B, 0, stream>>>(g2, fw3, fb3, fc3o, N);
    fc45_k<<<N, 1024, 0, stream>>>(fc3o, fw4, fb4, fw5, fb5, glob);

    // fusion + pointwise -> cell-major bilateral grid
    fusion_grid_k<<<(2*8*256*12 + B - 1)/B, B, 0, stream>>>(loc, glob, pw, pb, gridc);

    // full-res guide + slice + apply (4 px/thread)
    guide_slice_apply4_k<<<(2*1024*256)/B, B, 0, stream>>>(fullres, gridc, M, Mb,
        thr, slp, gbias, (float*)d_out);
}